// Round 11
// baseline (508.620 us; speedup 1.0000x reference)
//
#include <hip/hip_runtime.h>

#define N_NODES 50000
#define N_EDGES 400000
#define EMB 32
#define NREL 8
#define NLAYER 5
#define NPB 16          // node slots per block (8 waves x 2 sequential nodes)
#define KROWS 43        // 0..31 P, 32 Stot, 33..40 S_r, 41 h_dst(rgcnRoot), 42 h_dst(nnRoot)
#define NCHUNK 196      // ceil(50000/256) scan chunks

typedef __attribute__((ext_vector_type(8))) short short8;   // 8 bf16 (4 VGPRs)
typedef __attribute__((ext_vector_type(4))) float f32x4;    // MFMA accumulator

__device__ __forceinline__ unsigned short f2bf(float f) {   // RNE f32 -> bf16
    unsigned u = __float_as_uint(f);
    unsigned r = u + 0x7FFF + ((u >> 16) & 1);
    return (unsigned short)(r >> 16);
}

// ---------------- setup kernels ----------------

__global__ __launch_bounds__(256) void zero_kernel(int* __restrict__ p, int n) {
    int i = blockIdx.x * 256 + threadIdx.x;
    if (i < n) p[i] = 0;
}

__global__ __launch_bounds__(256) void hist_kernel(const int* __restrict__ ei,
                                                   const int* __restrict__ et,
                                                   int* __restrict__ deg,
                                                   int* __restrict__ relcnt) {
    int e = blockIdx.x * 256 + threadIdx.x;
    if (e < N_EDGES) {
        int d = ei[N_EDGES + e];           // dst = edge_index[1]
        atomicAdd(&deg[d], 1);
        atomicAdd(&relcnt[d * NREL + et[e]], 1);
    }
}

// per-chunk sum of deg
__global__ __launch_bounds__(256) void bsum_kernel(const int* __restrict__ deg,
                                                   int* __restrict__ bsum) {
    __shared__ int wsum[4];
    int tid = threadIdx.x, lane = tid & 63, w = tid >> 6;
    int i = blockIdx.x * 256 + tid;
    int v = (i < N_NODES) ? deg[i] : 0;
    #pragma unroll
    for (int off = 32; off > 0; off >>= 1) v += __shfl_down(v, off, 64);
    if (lane == 0) wsum[w] = v;
    __syncthreads();
    if (tid == 0) bsum[blockIdx.x] = wsum[0] + wsum[1] + wsum[2] + wsum[3];
}

// scan chunk sums -> boff; row_ptr[N]=E
__global__ __launch_bounds__(256) void boff_kernel(const int* __restrict__ bsum,
                                                   int* __restrict__ boff,
                                                   int* __restrict__ row_ptr) {
    __shared__ int ws[4];
    int tid = threadIdx.x, lane = tid & 63, w = tid >> 6;
    int v = (tid < NCHUNK) ? bsum[tid] : 0;
    int incl = v;
    #pragma unroll
    for (int off = 1; off < 64; off <<= 1) {
        int t = __shfl_up(incl, off, 64);
        if (lane >= off) incl += t;
    }
    if (lane == 63) ws[w] = incl;
    __syncthreads();
    int add = 0;
    for (int j = 0; j < w; j++) add += ws[j];
    if (tid < NCHUNK) boff[tid] = add + incl - v;
    if (tid == 0) row_ptr[N_NODES] = N_EDGES;
}

// per-chunk exclusive scan + chunk offset -> row_ptr
__global__ __launch_bounds__(256) void rptr_kernel(const int* __restrict__ deg,
                                                   const int* __restrict__ boff,
                                                   int* __restrict__ row_ptr) {
    __shared__ int ws[4];
    int tid = threadIdx.x, lane = tid & 63, w = tid >> 6;
    int i = blockIdx.x * 256 + tid;
    int v = (i < N_NODES) ? deg[i] : 0;
    int incl = v;
    #pragma unroll
    for (int off = 1; off < 64; off <<= 1) {
        int t = __shfl_up(incl, off, 64);
        if (lane >= off) incl += t;
    }
    if (lane == 63) ws[w] = incl;
    __syncthreads();
    int add = boff[blockIdx.x];
    for (int j = 0; j < w; j++) add += ws[j];
    if (i < N_NODES) row_ptr[i] = add + incl - v;
}

__global__ __launch_bounds__(256) void inv_kernel(const int* __restrict__ deg,
                                                  const int* __restrict__ relcnt,
                                                  float* __restrict__ invdeg,
                                                  float* __restrict__ invcnt) {
    int n = blockIdx.x * 256 + threadIdx.x;
    if (n < N_NODES) {
        int d = deg[n];
        invdeg[n] = 1.0f / (float)(d > 0 ? d : 1);
        #pragma unroll
        for (int r = 0; r < NREL; r++) {
            int c = relcnt[n * NREL + r];
            invcnt[n * NREL + r] = 1.0f / (float)(c > 0 ? c : 1);
        }
    }
}

__global__ __launch_bounds__(256) void scatter_kernel(const int* __restrict__ ei,
                                                      const int* __restrict__ et,
                                                      const float* __restrict__ ed,
                                                      const int* __restrict__ row_ptr,
                                                      int* __restrict__ cursor,
                                                      int2* __restrict__ edge2) {
    int e = blockIdx.x * 256 + threadIdx.x;
    if (e < N_EDGES) {
        int d = ei[N_EDGES + e];
        int pos = row_ptr[d] + atomicAdd(&cursor[d], 1);
        edge2[pos] = make_int2(ei[e] | (et[e] << 16), __float_as_int(ed[e]));
    }
}

// transpose+bf16 contraction weights: WB[m][o*32+i] = bf16(src_m[i*32+o])
// m 0..31: W2 rows; 32: b2; 33+l*10+j: j<8 rgcnW[l][j], j==8 rgcnRoot[l], j==9 nnRoot[l]
__global__ __launch_bounds__(256) void wtbf_kernel(const float* __restrict__ W2,
                                                   const float* __restrict__ b2,
                                                   const float* __restrict__ rgcnW,
                                                   const float* __restrict__ rgcnRoot,
                                                   const float* __restrict__ nnRoot,
                                                   unsigned short* __restrict__ WB) {
    int m = blockIdx.x;
    const float* src;
    if (m < 32) src = W2 + (size_t)m * 1024;
    else if (m == 32) src = b2;
    else {
        int t = m - 33, l = t / 10, j = t % 10;
        src = (j < 8) ? rgcnW + (size_t)(l * 8 + j) * 1024
            : (j == 8) ? rgcnRoot + (size_t)l * 1024
                       : nnRoot + (size_t)l * 1024;
    }
    unsigned short* dst = WB + (size_t)m * 1024;
    #pragma unroll
    for (int c = 0; c < 4; c++) {
        int idx = c * 256 + threadIdx.x;
        int o = idx >> 5, i = idx & 31;
        dst[o * 32 + i] = f2bf(src[i * 32 + o]);
    }
}

// ---------------- fc: h0 = relu(x @ fc_W + fc_b), + bf16 mirror ----------------

__global__ __launch_bounds__(256) void fc_kernel(const float* __restrict__ x,
                                                 const float* __restrict__ W,
                                                 const float* __restrict__ b,
                                                 float* __restrict__ h,
                                                 unsigned short* __restrict__ hb) {
    __shared__ __align__(16) float xt[8][EMB];
    int tid = threadIdx.x;
    int nl = tid >> 5, lane = tid & 31;
    int n0 = blockIdx.x * 8;
    xt[tid >> 5][tid & 31] = x[n0 * EMB + tid];
    __syncthreads();
    float acc = b[lane];
    #pragma unroll
    for (int i = 0; i < EMB; i++) acc += xt[nl][i] * W[i * EMB + lane];
    float v = fmaxf(acc, 0.0f);
    h[(n0 + nl) * EMB + lane] = v;
    hb[(n0 + nl) * EMB + lane] = f2bf(v);
}

// ---------------- fused layer kernel (MFMA edge phase + MFMA contraction) ----------------
// Per wave: 2 node slots (wv, wv+8), each node's edges in K=32 chunks via
// mfma_f32_16x16x32_bf16 (validated layout: A[m=lane&15][k=quad*8+j],
// B[n=lane&15][k=quad*8+j], C[row=quad*4+reg][col=lane&15]):
//   P  = Hid(32 x K) x Hvbf(K x 32)      (4 MFMAs: 2 M-tiles x 2 N-tiles)
//   S  = A2(16 x K)  x Hvbf(K x 32)      (2 MFMAs; A2 rows: 0..7 onehot(r), 8 ones)
// hid recomputed per edge from LDS-staged W1 (3 FMA). hv from bf16 mirror hbf.
// A-rows written bf16 pre-scaled; contraction/reduction/epilogue = R10-exact.
__global__ __launch_bounds__(512, 2) void layer_kernel(
    const float* __restrict__ h,
    const unsigned short* __restrict__ hbf,
    const int2* __restrict__ edge2,
    const int* __restrict__ row_ptr,
    const float* __restrict__ invdeg,
    const float* __restrict__ invcnt,
    const float* __restrict__ W1,
    const float* __restrict__ b1,
    const unsigned short* __restrict__ WBs,   // rows 0..32 (W2^T, b2^T)
    const unsigned short* __restrict__ WBl,   // rows 33..42 (rgcnW^T x8, rgcnRoot^T, nnRoot^T)
    const float* __restrict__ rgcnBias_l,
    const float* __restrict__ nnBias_l,
    float* __restrict__ hout,
    unsigned short* __restrict__ hbfout)
{
    __shared__ __align__(16) unsigned short P_lds[NPB][KROWS][EMB];  // 44032 B
    __shared__ __align__(16) float W1s[9 * EMB];                     // 1152 B
    // total 45184 B -> 3 blocks/CU

    const int tid = threadIdx.x;
    const int n0 = blockIdx.x * NPB;
    const int wv = tid >> 6;          // wave 0..7
    const int l64 = tid & 63;
    const int quad = l64 >> 4;
    const int col = l64 & 15;

    if (tid < 9 * EMB) W1s[tid] = W1[tid];
    __syncthreads();

    const float w10a = W1s[col], w10b = W1s[col + 16];
    const float b1a = b1[col], b1b = b1[col + 16];
    const short one_bf = (short)0x3F80;
    const short base8 = (col == 8) ? one_bf : (short)0;

    // ---------- edge phase: 2 nodes per wave, MFMA outer products ----------
    #pragma unroll 1
    for (int t = 0; t < 2; t++) {
        const int s = wv + 8 * t;
        const int n = n0 + s;
        const int pb = row_ptr[n], pe = row_ptr[n + 1];

        f32x4 Pc00 = {0,0,0,0}, Pc01 = {0,0,0,0};
        f32x4 Pc10 = {0,0,0,0}, Pc11 = {0,0,0,0};
        f32x4 Sc0  = {0,0,0,0}, Sc1  = {0,0,0,0};

        for (int base = pb; base < pe; base += 32) {
            int srcs[8];
            float hida[8], hidb[8];
            short8 A2v;
            #pragma unroll
            for (int j = 0; j < 8; j++) {
                int ei_ = base + quad * 8 + j;
                bool val = ei_ < pe;
                int2 em = edge2[val ? ei_ : pe - 1];
                int r = (em.x >> 16) & 7;
                srcs[j] = em.x & 0xFFFF;
                float dist = __int_as_float(em.y);
                float w1ra = W1s[(1 + r) * EMB + col];
                float w1rb = W1s[(1 + r) * EMB + col + 16];
                float ha = fmaxf(fmaf(dist, w10a, w1ra + b1a), 0.0f);
                float hb = fmaxf(fmaf(dist, w10b, w1rb + b1b), 0.0f);
                hida[j] = val ? ha : 0.0f;
                hidb[j] = val ? hb : 0.0f;
                A2v[j] = val ? ((col < 8) ? ((r == col) ? one_bf : (short)0) : base8)
                             : (short)0;
            }
            short8 B0, B1;
            #pragma unroll
            for (int j = 0; j < 8; j++) {
                const unsigned short* hp = hbf + (size_t)srcs[j] * EMB + col;
                B0[j] = (short)hp[0];
                B1[j] = (short)hp[16];
            }
            short8 A0, A1;
            #pragma unroll
            for (int j = 0; j < 8; j++) {
                A0[j] = (short)f2bf(hida[j]);
                A1[j] = (short)f2bf(hidb[j]);
            }
            Pc00 = __builtin_amdgcn_mfma_f32_16x16x32_bf16(A0, B0, Pc00, 0, 0, 0);
            Pc01 = __builtin_amdgcn_mfma_f32_16x16x32_bf16(A0, B1, Pc01, 0, 0, 0);
            Pc10 = __builtin_amdgcn_mfma_f32_16x16x32_bf16(A1, B0, Pc10, 0, 0, 0);
            Pc11 = __builtin_amdgcn_mfma_f32_16x16x32_bf16(A1, B1, Pc11, 0, 0, 0);
            Sc0  = __builtin_amdgcn_mfma_f32_16x16x32_bf16(A2v, B0, Sc0, 0, 0, 0);
            Sc1  = __builtin_amdgcn_mfma_f32_16x16x32_bf16(A2v, B1, Sc1, 0, 0, 0);
        }

        // ---------- write bf16 A-rows for slot s (pre-scaled) ----------
        const float idg = invdeg[n];
        #pragma unroll
        for (int reg = 0; reg < 4; reg++) {
            int m = quad * 4 + reg;           // C row within tile
            P_lds[s][m][col]           = f2bf(Pc00[reg] * idg);
            P_lds[s][m][col + 16]      = f2bf(Pc01[reg] * idg);
            P_lds[s][m + 16][col]      = f2bf(Pc10[reg] * idg);
            P_lds[s][m + 16][col + 16] = f2bf(Pc11[reg] * idg);
        }
        #pragma unroll
        for (int reg = 0; reg < 4; reg++) {
            int m = quad * 4 + reg;
            if (m < 8) {                      // S_r rows (quads 0,1)
                float ic = invcnt[n * NREL + m];
                P_lds[s][33 + m][col]      = f2bf(Sc0[reg] * ic);
                P_lds[s][33 + m][col + 16] = f2bf(Sc1[reg] * ic);
            } else if (m == 8) {              // Stot row (quad 2, reg 0)
                P_lds[s][32][col]      = f2bf(Sc0[reg] * idg);
                P_lds[s][32][col + 16] = f2bf(Sc1[reg] * idg);
            }
        }
        {   // h_dst rows 41/42 straight from bf16 mirror
            int i = l64 & 31;
            int row = 41 + (l64 >> 5);
            P_lds[s][row][i] = hbf[(size_t)n * EMB + i];
        }
    }
    __syncthreads();

    // ---------- MFMA contraction (R10-exact) ----------
    const int node16 = l64 & 15;
    const int o0 = l64 & 15;                  // B n-index (tile 0); tile 1 = +16

    f32x4 accN0 = {0.f, 0.f, 0.f, 0.f}, accN1 = {0.f, 0.f, 0.f, 0.f};
    f32x4 accR0 = {0.f, 0.f, 0.f, 0.f}, accR1 = {0.f, 0.f, 0.f, 0.f};

    #pragma unroll
    for (int j = 0; j < 6; j++) {
        const int rr = wv + 8 * j;            // wave-uniform
        if (rr < KROWS) {
            const unsigned short* Bsrc = (rr < 33) ? (WBs + (size_t)rr * 1024)
                                                   : (WBl + (size_t)(rr - 33) * 1024);
            short8 bf0 = *(const short8*)(Bsrc + o0 * 32 + quad * 8);
            short8 bf1 = *(const short8*)(Bsrc + (o0 + 16) * 32 + quad * 8);
            short8 a = *(const short8*)&P_lds[node16][rr][quad * 8];
            if (rr <= 32 || rr == 42) {
                accN0 = __builtin_amdgcn_mfma_f32_16x16x32_bf16(a, bf0, accN0, 0, 0, 0);
                accN1 = __builtin_amdgcn_mfma_f32_16x16x32_bf16(a, bf1, accN1, 0, 0, 0);
            } else {
                accR0 = __builtin_amdgcn_mfma_f32_16x16x32_bf16(a, bf0, accR0, 0, 0, 0);
                accR1 = __builtin_amdgcn_mfma_f32_16x16x32_bf16(a, bf1, accR1, 0, 0, 0);
            }
        }
    }
    __syncthreads();                          // all A-reads done; safe to overlay RedAll

    // ---------- deterministic cross-wave reduction (no atomics) ----------
    float* RedAll = (float*)&P_lds[0][0][0];  // 8 waves x 1024 floats = 32 KiB < 44 KiB
    {
        float* my = RedAll + wv * 1024;
        #pragma unroll
        for (int reg = 0; reg < 4; reg++) {
            int nd = quad * 4 + reg;          // C/D: row(m=node)=quad*4+reg, col(n=o)=lane&15
            my[nd * 32 + o0]            = accN0[reg];
            my[nd * 32 + o0 + 16]       = accN1[reg];
            my[512 + nd * 32 + o0]      = accR0[reg];
            my[512 + nd * 32 + o0 + 16] = accR1[reg];
        }
    }
    __syncthreads();

    // ---------- epilogue (node slot = tid>>5, output col = tid&31) ----------
    {
        float sn = 0.0f, sr = 0.0f;
        #pragma unroll
        for (int ww = 0; ww < 8; ww++) {
            sn += RedAll[ww * 1024 + tid];          // stride-1, conflict-free
            sr += RedAll[ww * 1024 + 512 + tid];
        }
        int node = n0 + (tid >> 5), o = tid & 31;
        float hd = h[node * EMB + o];               // coalesced
        float o_r = fmaxf(sr + rgcnBias_l[o], 0.0f);
        float o_n = fmaxf(sn + nnBias_l[o], 0.0f);
        float out = hd + o_r + o_n;
        hout[node * EMB + o] = out;
        hbfout[node * EMB + o] = f2bf(out);
    }
}

// ---------------- launch ----------------

extern "C" void kernel_launch(void* const* d_in, const int* in_sizes, int n_in,
                              void* d_out, int out_size, void* d_ws, size_t ws_size,
                              hipStream_t stream) {
    const float* x        = (const float*)d_in[0];
    const int*   ei       = (const int*)d_in[1];
    const int*   et       = (const int*)d_in[2];
    const float* ed       = (const float*)d_in[3];
    const float* fcW      = (const float*)d_in[4];
    const float* fcb      = (const float*)d_in[5];
    const float* rgcnW    = (const float*)d_in[6];
    const float* rgcnRoot = (const float*)d_in[7];
    const float* rgcnBias = (const float*)d_in[8];
    const float* W1       = (const float*)d_in[9];
    const float* b1       = (const float*)d_in[10];
    const float* W2       = (const float*)d_in[11];
    const float* b2       = (const float*)d_in[12];
    const float* nnRoot   = (const float*)d_in[13];
    const float* nnBias   = (const float*)d_in[14];

    float* ws = (float*)d_ws;
    float* h_a    = ws;  ws += (size_t)N_NODES * EMB;
    float* h_b    = ws;  ws += (size_t)N_NODES * EMB;
    float* invdeg = ws;  ws += (size_t)N_NODES;
    float* invcnt = ws;  ws += (size_t)N_NODES * NREL;
    unsigned short* WB = (unsigned short*)ws;  ws += (size_t)83 * 1024 / 2;  // 83 rows bf16
    unsigned short* hbf_a = (unsigned short*)ws;  ws += (size_t)N_NODES * EMB / 2;
    unsigned short* hbf_b = (unsigned short*)ws;  ws += (size_t)N_NODES * EMB / 2;
    int2* edge2   = (int2*)ws;     ws += (size_t)N_EDGES * 2;
    int* row_ptr  = (int*)ws;      ws += (size_t)(N_NODES + 1);
    int* bsum     = (int*)ws;      ws += (size_t)NCHUNK;
    int* boff     = (int*)ws;      ws += (size_t)NCHUNK;
    int* deg      = (int*)ws;      ws += (size_t)N_NODES;       // deg..cursor contiguous (zeroed)
    int* relcnt   = (int*)ws;      ws += (size_t)N_NODES * NREL;
    int* cursor   = (int*)ws;      ws += (size_t)N_NODES;
    (void)in_sizes; (void)n_in; (void)out_size; (void)ws_size;

    zero_kernel<<<(10 * N_NODES + 255) / 256, 256, 0, stream>>>(deg, 10 * N_NODES);
    hist_kernel<<<(N_EDGES + 255) / 256, 256, 0, stream>>>(ei, et, deg, relcnt);
    bsum_kernel<<<NCHUNK, 256, 0, stream>>>(deg, bsum);
    inv_kernel<<<(N_NODES + 255) / 256, 256, 0, stream>>>(deg, relcnt, invdeg, invcnt);
    boff_kernel<<<1, 256, 0, stream>>>(bsum, boff, row_ptr);
    rptr_kernel<<<NCHUNK, 256, 0, stream>>>(deg, boff, row_ptr);
    scatter_kernel<<<(N_EDGES + 255) / 256, 256, 0, stream>>>(ei, et, ed, row_ptr,
                                                              cursor, edge2);
    wtbf_kernel<<<83, 256, 0, stream>>>(W2, b2, rgcnW, rgcnRoot, nnRoot, WB);
    fc_kernel<<<N_NODES / 8, 256, 0, stream>>>(x, fcW, fcb, h_a, hbf_a);

    const float* hin = h_a;
    const unsigned short* hbf_in = hbf_a;
    float* houtb = h_b;
    unsigned short* hbf_out = hbf_b;
    for (int l = 0; l < NLAYER; l++) {
        float* dst = (l == NLAYER - 1) ? (float*)d_out : houtb;
        layer_kernel<<<N_NODES / NPB, 512, 0, stream>>>(
            hin, hbf_in, edge2, row_ptr, invdeg, invcnt, W1, b1,
            WB, WB + (size_t)(33 + l * 10) * 1024,
            rgcnBias + (size_t)l * EMB,
            nnBias + (size_t)l * EMB,
            dst, hbf_out);
        float* old_in = (float*)hin;
        unsigned short* old_hbf = (unsigned short*)hbf_in;
        hin = dst;
        hbf_in = hbf_out;
        houtb = old_in;
        hbf_out = old_hbf;
    }
}